// Round 8
// baseline (157.095 us; speedup 1.0000x reference)
//
#include <hip/hip_runtime.h>

// GAT forward, O(N*HD) via rank decomposition. B=8,N=1024,F=128,H=4,HD=32.
// score(i,j)=s_i+d_j; negative iff d_j < -s_i. Per (b,h), rank j by (d_j,j) lex:
//   out[i,:] = (c2*PB[k_i] + c1*SufA[k_i]) / (c2*sPB[k_i] + c1*sSF[k_i])
// PB: exclusive prefix of e^{0.2d}*h over sorted order (chunk-local tbl + LDS offs);
// SufA: inclusive suffix of e^{d}*h; sPB/sSF: scalar versions, computed exactly
// in the rank kernel (same predicate as the rank count). k_i = lower_bound(-s_i).

constexpr int CB  = 8;
constexpr int CN  = 1024;
constexpr int CF  = 128;
constexpr int CH  = 4;
constexpr int CHD = 32;
constexpr int CBH = CB * CH;        // 32
constexpr int CROWS = CB * CN;      // 8192
constexpr int TROWS = CN + 1;       // 1025 (row 1024 = zeros)
constexpr int SS    = CN + 1;       // scalar-scan stride

// ---------------- K1: projection + s/d + exp coefficients ----------------
// 512 blocks x 256 thr; tile 16 rows x 128 cols; thread = 2 rows x 4 cols.
// x via padded LDS broadcast; W via coalesced global float4 (L2-hot).
__global__ __launch_bounds__(256) void proj_kernel(
    const float* __restrict__ x, const float* __restrict__ W,
    const float* __restrict__ a_src, const float* __restrict__ a_dst,
    float* __restrict__ h_ws, float* __restrict__ sarr, float* __restrict__ darr,
    float* __restrict__ cfF, float* __restrict__ cfB)
{
    __shared__ __align__(16) float xs[16 * 132];
    const int tid = threadIdx.x;
    const int row0 = blockIdx.x * 16;

    const float4* x4 = (const float4*)x;
    #pragma unroll
    for (int m = 0; m < 2; ++m) {
        const int idx = m * 256 + tid;
        const int r = idx >> 5, k4 = idx & 31;
        *(float4*)(xs + r * 132 + k4 * 4) = x4[(size_t)(row0 + r) * 32 + k4];
    }
    __syncthreads();

    const int c4 = tid & 31, rp = tid >> 5;
    float acc0[4] = {0.f,0.f,0.f,0.f};
    float acc1[4] = {0.f,0.f,0.f,0.f};
    const float* xr0 = xs + (rp * 2) * 132;
    const float* xr1 = xs + (rp * 2 + 1) * 132;

    #pragma unroll 4
    for (int k4 = 0; k4 < 32; ++k4) {
        const float4 xv0 = *(const float4*)(xr0 + k4 * 4);
        const float4 xv1 = *(const float4*)(xr1 + k4 * 4);
        const float xq0[4] = {xv0.x, xv0.y, xv0.z, xv0.w};
        const float xq1[4] = {xv1.x, xv1.y, xv1.z, xv1.w};
        #pragma unroll
        for (int q = 0; q < 4; ++q) {
            const float4 wq = *(const float4*)(W + (size_t)(k4 * 4 + q) * CF + c4 * 4);
            acc0[0] += xq0[q] * wq.x; acc0[1] += xq0[q] * wq.y;
            acc0[2] += xq0[q] * wq.z; acc0[3] += xq0[q] * wq.w;
            acc1[0] += xq1[q] * wq.x; acc1[1] += xq1[q] * wq.y;
            acc1[2] += xq1[q] * wq.z; acc1[3] += xq1[q] * wq.w;
        }
    }

    const float4 av = *(const float4*)(a_src + c4 * 4);
    const float4 dv = *(const float4*)(a_dst + c4 * 4);
    float s0 = acc0[0]*av.x + acc0[1]*av.y + acc0[2]*av.z + acc0[3]*av.w;
    float d0 = acc0[0]*dv.x + acc0[1]*dv.y + acc0[2]*dv.z + acc0[3]*dv.w;
    float s1 = acc1[0]*av.x + acc1[1]*av.y + acc1[2]*av.z + acc1[3]*av.w;
    float d1 = acc1[0]*dv.x + acc1[1]*dv.y + acc1[2]*dv.z + acc1[3]*dv.w;
    #pragma unroll
    for (int m = 1; m <= 4; m <<= 1) {
        s0 += __shfl_xor(s0, m); d0 += __shfl_xor(d0, m);
        s1 += __shfl_xor(s1, m); d1 += __shfl_xor(d1, m);
    }

    const int head = c4 >> 3, dd0 = (c4 & 7) * 4;
    #pragma unroll
    for (int r2 = 0; r2 < 2; ++r2) {
        const int row = row0 + rp * 2 + r2, b = row >> 10, n = row & 1023;
        const int bh = b * CH + head;
        const float* a = r2 ? acc1 : acc0;
        *(float4*)(h_ws + (size_t)(bh * CN + n) * CHD + dd0)
            = make_float4(a[0], a[1], a[2], a[3]);
        if ((c4 & 7) == 0) {
            const float sv = r2 ? s1 : s0, dvv = r2 ? d1 : d0;
            sarr[bh * CN + n] = sv;
            darr[bh * CN + n] = dvv;
            cfF[bh * CN + n] = __expf(0.2f * dvv);
            cfB[bh * CN + n] = __expf(dvv);
        }
    }
}

// ---------------- K2: rank + scalar scans + scatter ----------------
// 256 blocks x 256 thr (1 blk/CU). Block = (bh, oct of 128 i's). Thread =
// (j-slice s of 128, i-quad q): 4 i's amortize each LDS read. pred = (dj,j)
// <lex (di,i); cnt += pred; sPB += pred*cfF[j]; sSF += !pred*cfB[j] (includes
// j==i -> inclusive suffix). Combine 8 slices via LDS; scatter by rank.
__global__ __launch_bounds__(256) void rank_kernel(
    const float* __restrict__ darr, const float* __restrict__ cfF,
    const float* __restrict__ cfB,
    float* __restrict__ dsrt, int* __restrict__ perm,
    float* __restrict__ cfFs, float* __restrict__ cfBs,
    float* __restrict__ sPBs, float* __restrict__ sSFs)
{
    __shared__ __align__(16) float dsh[CN];
    __shared__ __align__(16) float fsh[CN];
    __shared__ __align__(16) float bsh[CN];
    __shared__ float cntP[8 * 128], pbP[8 * 128], sfP[8 * 128];

    const int bh = blockIdx.x >> 3, oct = blockIdx.x & 7;
    const int tid = threadIdx.x;
    for (int t = tid; t < CN; t += 256) {
        dsh[t] = darr[bh * CN + t];
        fsh[t] = cfF[bh * CN + t];
        bsh[t] = cfB[bh * CN + t];
    }
    __syncthreads();

    const int q = tid & 31, s = tid >> 5;
    const int i0 = oct * 128 + q * 4;
    const float di0 = dsh[i0], di1 = dsh[i0+1], di2 = dsh[i0+2], di3 = dsh[i0+3];
    int   cnt[4] = {0,0,0,0};
    float pb[4]  = {0.f,0.f,0.f,0.f};
    float sf[4]  = {0.f,0.f,0.f,0.f};
    const float dii[4] = {di0, di1, di2, di3};

    const int jb0 = s * 128;
    #pragma unroll 2
    for (int t = 0; t < 32; ++t) {
        const int j0 = jb0 + t * 4;
        const float4 d4 = *(const float4*)(dsh + j0);   // half-wave broadcast
        const float4 f4 = *(const float4*)(fsh + j0);
        const float4 b4 = *(const float4*)(bsh + j0);
        const float dj[4] = {d4.x, d4.y, d4.z, d4.w};
        const float fj[4] = {f4.x, f4.y, f4.z, f4.w};
        const float bj[4] = {b4.x, b4.y, b4.z, b4.w};
        #pragma unroll
        for (int a = 0; a < 4; ++a) {
            #pragma unroll
            for (int r = 0; r < 4; ++r) {
                const bool pred = (dj[a] < dii[r]) ||
                                  (dj[a] == dii[r] && (j0 + a) < (i0 + r));
                cnt[r] += pred ? 1 : 0;
                pb[r]  += pred ? fj[a] : 0.f;
                sf[r]  += pred ? 0.f : bj[a];
            }
        }
    }
    #pragma unroll
    for (int r = 0; r < 4; ++r) {
        cntP[s * 128 + q * 4 + r] = (float)cnt[r];
        pbP [s * 128 + q * 4 + r] = pb[r];
        sfP [s * 128 + q * 4 + r] = sf[r];
    }
    __syncthreads();

    if (tid < 128) {
        const int i = oct * 128 + tid;
        int c = 0; float pbt = 0.f, sft = 0.f;
        #pragma unroll
        for (int s2 = 0; s2 < 8; ++s2) {
            c   += (int)cntP[s2 * 128 + tid];
            pbt += pbP[s2 * 128 + tid];
            sft += sfP[s2 * 128 + tid];
        }
        const float d_i = dsh[i], f_i = fsh[i], b_i = bsh[i];
        const int r = bh * CN + c;
        dsrt[r] = d_i;
        perm[r] = i;
        cfFs[r] = f_i;
        cfBs[r] = b_i;
        sPBs[bh * SS + c] = pbt;
        sSFs[bh * SS + c] = sft;
        if (c == CN - 1) { sPBs[bh * SS + CN] = pbt + f_i; sSFs[bh * SS + CN] = 0.f; }
    }
}

// ---------------- K3: tail — chunk scans + offsets + search + combine --------
// 32 blocks x 1024 thr (4 waves/SIMD on the CUs used). tbl round-trips through
// same-CU L2 (validated R4/R5). Offsets computed ONCE per bh in LDS.
__global__ __launch_bounds__(1024) void tail_kernel(
    const float* __restrict__ h_ws, const float* __restrict__ sarr,
    const float* __restrict__ dsrt, const int* __restrict__ perm,
    const float* __restrict__ cfFs, const float* __restrict__ cfBs,
    const float* __restrict__ sPBs, const float* __restrict__ sSFs,
    float* __restrict__ tbl_g, float* __restrict__ out)
{
    __shared__ __align__(16) float dsS[CN];
    __shared__ int   pjS[CN];
    __shared__ float cfS[CN];
    __shared__ float cbS[CN];
    __shared__ float pbS[SS + 3];
    __shared__ float sfS[SS + 3];
    __shared__ float ctF[32 * 32], ctB[32 * 32];
    __shared__ float ofF[33 * 32], ofB[33 * 32];

    const int bh = blockIdx.x, tid = threadIdx.x;
    float* __restrict__ tbl = tbl_g + (size_t)bh * TROWS * 64;

    dsS[tid] = dsrt[bh * CN + tid];
    pjS[tid] = perm[bh * CN + tid];
    cfS[tid] = cfFs[bh * CN + tid];
    cbS[tid] = cfBs[bh * CN + tid];
    pbS[tid] = sPBs[bh * SS + tid];
    sfS[tid] = sSFs[bh * SS + tid];
    if (tid == 0) { pbS[CN] = sPBs[bh * SS + CN]; sfS[CN] = sSFs[bh * SS + CN]; }
    if (tid < 64) tbl[(size_t)CN * 64 + tid] = 0.f;   // virtual row 1024
    __syncthreads();

    const int c = tid >> 5, dd = tid & 31;
    const float* __restrict__ hb = h_ws + (size_t)bh * CN * CHD;

    {   // forward: exclusive prefix of cfF*h within chunk c
        float acc = 0.f;
        #pragma unroll
        for (int g = 0; g < 4; ++g) {
            float hv[8], cv[8];
            #pragma unroll
            for (int t = 0; t < 8; ++t) {
                const int pos = c * 32 + g * 8 + t;
                hv[t] = hb[(size_t)pjS[pos] * CHD + dd];   // 8 gathers in flight
                cv[t] = cfS[pos];
            }
            #pragma unroll
            for (int t = 0; t < 8; ++t) {
                const int pos = c * 32 + g * 8 + t;
                tbl[(size_t)pos * 64 + dd] = acc;
                acc += cv[t] * hv[t];
            }
        }
        ctF[c * 32 + dd] = acc;
    }
    {   // backward: inclusive suffix of cfB*h within chunk c
        float acc = 0.f;
        #pragma unroll
        for (int g = 0; g < 4; ++g) {
            float hv[8], cv[8];
            #pragma unroll
            for (int t = 0; t < 8; ++t) {
                const int pos = c * 32 + 31 - (g * 8 + t);
                hv[t] = hb[(size_t)pjS[pos] * CHD + dd];
                cv[t] = cbS[pos];
            }
            #pragma unroll
            for (int t = 0; t < 8; ++t) {
                const int pos = c * 32 + 31 - (g * 8 + t);
                acc += cv[t] * hv[t];
                tbl[(size_t)pos * 64 + 32 + dd] = acc;
            }
        }
        ctB[c * 32 + dd] = acc;
    }
    __syncthreads();

    {   // chunk offsets (once per bh)
        float rF = 0.f;
        for (int c2 = 0; c2 < c; ++c2) rF += ctF[c2 * 32 + dd];
        ofF[c * 32 + dd] = rF;
        if (c == 31) ofF[32 * 32 + dd] = rF + ctF[31 * 32 + dd];
        float rB = 0.f;
        for (int c2 = c + 1; c2 < 32; ++c2) rB += ctB[c2 * 32 + dd];
        ofB[c * 32 + dd] = rB;
        if (c == 0) ofB[32 * 32 + dd] = 0.f;
    }
    __syncthreads();

    {   // binary search + gather + combine
        const int i = tid;
        const float s = sarr[bh * CN + i];
        const float c1 = __expf(s), c2v = __expf(0.2f * s), thr = -s;
        int lo = 0, hi = CN;
        while (lo < hi) { const int mid = (lo + hi) >> 1; if (dsS[mid] < thr) lo = mid + 1; else hi = mid; }
        const int k = lo, kc = k >> 5;                 // 0..32 (k==1024 -> 32)

        const float PBs = pbS[k], SFs = sfS[k];
        const float inv = 1.0f / (c2v * PBs + c1 * SFs);

        const float4* tr = (const float4*)(tbl + (size_t)k * 64);
        const int b = bh >> 2, hh = bh & 3;
        float4* o = (float4*)(out + (size_t)(b * CN + i) * CF + hh * 32);
        #pragma unroll
        for (int qq = 0; qq < 8; ++qq) {
            const float4 pb4 = tr[qq], sf4 = tr[8 + qq];
            const float4 oa = *(const float4*)(&ofF[kc * 32 + qq * 4]);
            const float4 ob = *(const float4*)(&ofB[kc * 32 + qq * 4]);
            float4 r;
            r.x = (c2v * (pb4.x + oa.x) + c1 * (sf4.x + ob.x)) * inv;
            r.y = (c2v * (pb4.y + oa.y) + c1 * (sf4.y + ob.y)) * inv;
            r.z = (c2v * (pb4.z + oa.z) + c1 * (sf4.z + ob.z)) * inv;
            r.w = (c2v * (pb4.w + oa.w) + c1 * (sf4.w + ob.w)) * inv;
            o[qq] = r;
        }
    }
}

extern "C" void kernel_launch(void* const* d_in, const int* in_sizes, int n_in,
                              void* d_out, int out_size, void* d_ws, size_t ws_size,
                              hipStream_t stream) {
    const float* x     = (const float*)d_in[0];
    const float* W     = (const float*)d_in[1];
    const float* a_src = (const float*)d_in[2];
    const float* a_dst = (const float*)d_in[3];
    float* out = (float*)d_out;

    char* ws = (char*)d_ws;
    size_t off = 0;
    float* h_ws = (float*)(ws + off); off += (size_t)CROWS * CF * 4;            // 4 MB
    float* sarr = (float*)(ws + off); off += (size_t)CBH * CN * 4;
    float* darr = (float*)(ws + off); off += (size_t)CBH * CN * 4;
    float* cfF  = (float*)(ws + off); off += (size_t)CBH * CN * 4;
    float* cfB  = (float*)(ws + off); off += (size_t)CBH * CN * 4;
    float* dsrt = (float*)(ws + off); off += (size_t)CBH * CN * 4;
    int*   perm = (int*)  (ws + off); off += (size_t)CBH * CN * 4;
    float* cfFs = (float*)(ws + off); off += (size_t)CBH * CN * 4;
    float* cfBs = (float*)(ws + off); off += (size_t)CBH * CN * 4;
    float* sPBs = (float*)(ws + off); off += (size_t)CBH * SS * 4;
    float* sSFs = (float*)(ws + off); off += (size_t)CBH * SS * 4;
    float* tblg = (float*)(ws + off); off += (size_t)CBH * TROWS * 64 * 4;      // 8.4 MB
    (void)ws_size;

    proj_kernel<<<512, 256, 0, stream>>>(x, W, a_src, a_dst, h_ws, sarr, darr, cfF, cfB);
    rank_kernel<<<256, 256, 0, stream>>>(darr, cfF, cfB, dsrt, perm, cfFs, cfBs, sPBs, sSFs);
    tail_kernel<<<CBH, 1024, 0, stream>>>(h_ws, sarr, dsrt, perm, cfFs, cfBs, sPBs, sSFs, tblg, out);
}

// Round 9
// 124.315 us; speedup vs baseline: 1.2637x; 1.2637x over previous
//
#include <hip/hip_runtime.h>

// GAT forward, O(N*HD) via rank decomposition. B=8,N=1024,F=128,H=4,HD=32.
// score(i,j)=s_i+d_j; negative iff d_j < -s_i. Per (b,h), rank j by (d_j,j) lex:
//   out[i,:] = (c2*PB[k_i] + c1*SufA[k_i]) / (c2*sPB[k_i] + c1*sSF[k_i])
// PB: exclusive prefix of e^{0.2d}*h over rank order (chunk tbl + LDS offsets);
// SufA: inclusive suffix of e^{d}*h. sPB/sSF scalar sums fall out of the rank
// predicate for free. k_i = lower_bound(dsrt, -s_i); c1=e^{s_i}, c2=e^{0.2 s_i}.
// WIDTH RULE (R8 lesson): every kernel >= 2 blocks/CU, >= 8 waves/CU.

constexpr int CB  = 8;
constexpr int CN  = 1024;
constexpr int CF  = 128;
constexpr int CH  = 4;
constexpr int CHD = 32;
constexpr int CBH = CB * CH;        // 32
constexpr int CROWS = CB * CN;      // 8192
constexpr int TROWS = CN + 1;       // 1025 (row 1024 = zeros)
constexpr int SS    = CN + 1;

// ---------------- K1: projection + s/d + exp coefficients ----------------
// 512 blocks x 256 thr; tile 16 rows x 128 cols; thread = 2 rows x 4 cols.
__global__ __launch_bounds__(256) void proj_kernel(
    const float* __restrict__ x, const float* __restrict__ W,
    const float* __restrict__ a_src, const float* __restrict__ a_dst,
    float* __restrict__ h_ws, float* __restrict__ sarr, float* __restrict__ darr,
    float* __restrict__ cfF, float* __restrict__ cfB)
{
    __shared__ __align__(16) float xs[16 * 132];
    const int tid = threadIdx.x;
    const int row0 = blockIdx.x * 16;

    const float4* x4 = (const float4*)x;
    #pragma unroll
    for (int m = 0; m < 2; ++m) {
        const int idx = m * 256 + tid;
        const int r = idx >> 5, k4 = idx & 31;
        *(float4*)(xs + r * 132 + k4 * 4) = x4[(size_t)(row0 + r) * 32 + k4];
    }
    __syncthreads();

    const int c4 = tid & 31, rp = tid >> 5;
    float acc0[4] = {0.f,0.f,0.f,0.f};
    float acc1[4] = {0.f,0.f,0.f,0.f};
    const float* xr0 = xs + (rp * 2) * 132;
    const float* xr1 = xs + (rp * 2 + 1) * 132;

    #pragma unroll 4
    for (int k4 = 0; k4 < 32; ++k4) {
        const float4 xv0 = *(const float4*)(xr0 + k4 * 4);
        const float4 xv1 = *(const float4*)(xr1 + k4 * 4);
        const float xq0[4] = {xv0.x, xv0.y, xv0.z, xv0.w};
        const float xq1[4] = {xv1.x, xv1.y, xv1.z, xv1.w};
        #pragma unroll
        for (int q = 0; q < 4; ++q) {
            const float4 wq = *(const float4*)(W + (size_t)(k4 * 4 + q) * CF + c4 * 4);
            acc0[0] += xq0[q] * wq.x; acc0[1] += xq0[q] * wq.y;
            acc0[2] += xq0[q] * wq.z; acc0[3] += xq0[q] * wq.w;
            acc1[0] += xq1[q] * wq.x; acc1[1] += xq1[q] * wq.y;
            acc1[2] += xq1[q] * wq.z; acc1[3] += xq1[q] * wq.w;
        }
    }

    const float4 av = *(const float4*)(a_src + c4 * 4);
    const float4 dv = *(const float4*)(a_dst + c4 * 4);
    float s0 = acc0[0]*av.x + acc0[1]*av.y + acc0[2]*av.z + acc0[3]*av.w;
    float d0 = acc0[0]*dv.x + acc0[1]*dv.y + acc0[2]*dv.z + acc0[3]*dv.w;
    float s1 = acc1[0]*av.x + acc1[1]*av.y + acc1[2]*av.z + acc1[3]*av.w;
    float d1 = acc1[0]*dv.x + acc1[1]*dv.y + acc1[2]*dv.z + acc1[3]*dv.w;
    #pragma unroll
    for (int m = 1; m <= 4; m <<= 1) {
        s0 += __shfl_xor(s0, m); d0 += __shfl_xor(d0, m);
        s1 += __shfl_xor(s1, m); d1 += __shfl_xor(d1, m);
    }

    const int head = c4 >> 3, dd0 = (c4 & 7) * 4;
    #pragma unroll
    for (int r2 = 0; r2 < 2; ++r2) {
        const int row = row0 + rp * 2 + r2, b = row >> 10, n = row & 1023;
        const int bh = b * CH + head;
        const float* a = r2 ? acc1 : acc0;
        *(float4*)(h_ws + (size_t)(bh * CN + n) * CHD + dd0)
            = make_float4(a[0], a[1], a[2], a[3]);
        if ((c4 & 7) == 0) {
            const float sv = r2 ? s1 : s0, dvv = r2 ? d1 : d0;
            sarr[bh * CN + n] = sv;
            darr[bh * CN + n] = dvv;
            cfF[bh * CN + n] = __expf(0.2f * dvv);
            cfB[bh * CN + n] = __expf(dvv);
        }
    }
}

// ---------------- K2: rank + scalar sums + scatter ----------------
// 512 blocks x 256 thr (2 blk/CU, 8 waves/CU). Block = (bh, hex of 64 i's).
// Thread = (q=tid&15: i-quad, s=tid>>4: j-slice of 64). 256 pairs/thread.
// pred = (dj,j) <lex (di,i): cnt += pred; pb += pred*cfF; sf += !pred*cfB.
__global__ __launch_bounds__(256) void rank_kernel(
    const float* __restrict__ darr, const float* __restrict__ cfF,
    const float* __restrict__ cfB,
    float* __restrict__ dsrt, int* __restrict__ perm,
    float* __restrict__ cfFs, float* __restrict__ cfBs,
    float* __restrict__ sPBs, float* __restrict__ sSFs)
{
    __shared__ __align__(16) float dsh[CN];
    __shared__ __align__(16) float fsh[CN];
    __shared__ __align__(16) float bsh[CN];
    __shared__ float cntP[16 * 64], pbP[16 * 64], sfP[16 * 64];

    const int bh = blockIdx.x >> 4, hex = blockIdx.x & 15;
    const int tid = threadIdx.x;
    for (int t = tid; t < CN; t += 256) {
        dsh[t] = darr[bh * CN + t];
        fsh[t] = cfF[bh * CN + t];
        bsh[t] = cfB[bh * CN + t];
    }
    __syncthreads();

    const int q = tid & 15, s = tid >> 4;
    const int i0 = hex * 64 + q * 4;
    const float4 di4 = *(const float4*)(dsh + i0);
    const float dii[4] = {di4.x, di4.y, di4.z, di4.w};
    int   cnt[4] = {0,0,0,0};
    float pb[4]  = {0.f,0.f,0.f,0.f};
    float sf[4]  = {0.f,0.f,0.f,0.f};

    const int jb = s * 64;
    for (int t = 0; t < 16; ++t) {
        const int j0 = jb + t * 4;
        const float4 d4 = *(const float4*)(dsh + j0);
        const float4 f4 = *(const float4*)(fsh + j0);
        const float4 b4 = *(const float4*)(bsh + j0);
        const float dj[4] = {d4.x, d4.y, d4.z, d4.w};
        const float fj[4] = {f4.x, f4.y, f4.z, f4.w};
        const float bj[4] = {b4.x, b4.y, b4.z, b4.w};
        #pragma unroll
        for (int a = 0; a < 4; ++a) {
            #pragma unroll
            for (int r = 0; r < 4; ++r) {
                const bool pred = (dj[a] < dii[r]) ||
                                  (dj[a] == dii[r] && (j0 + a) < (i0 + r));
                cnt[r] += pred ? 1 : 0;
                pb[r]  += pred ? fj[a] : 0.f;
                sf[r]  += pred ? 0.f : bj[a];
            }
        }
    }
    #pragma unroll
    for (int r = 0; r < 4; ++r) {
        cntP[s * 64 + q * 4 + r] = (float)cnt[r];
        pbP [s * 64 + q * 4 + r] = pb[r];
        sfP [s * 64 + q * 4 + r] = sf[r];
    }
    __syncthreads();

    if (tid < 64) {
        const int i = hex * 64 + tid;
        int c = 0; float pbt = 0.f, sft = 0.f;
        #pragma unroll
        for (int s2 = 0; s2 < 16; ++s2) {
            c   += (int)cntP[s2 * 64 + tid];
            pbt += pbP[s2 * 64 + tid];
            sft += sfP[s2 * 64 + tid];
        }
        const float d_i = dsh[i], f_i = fsh[i], b_i = bsh[i];
        const int rk = bh * CN + c;
        dsrt[rk] = d_i;
        perm[rk] = i;
        cfFs[rk] = f_i;
        cfBs[rk] = b_i;
        sPBs[bh * SS + c] = pbt;
        sSFs[bh * SS + c] = sft;
        if (c == CN - 1) { sPBs[bh * SS + CN] = pbt + f_i; sSFs[bh * SS + CN] = 0.f; }
    }
}

// ---------------- K3: chunk-local vector scans ----------------
// 256 blocks x 256 thr; block = (bh, g): 4 chunks of 32 positions.
// thread = (sub, dir, dd); 16-deep gather batching.
__global__ __launch_bounds__(256) void scan_kernel(
    const float* __restrict__ h_ws, const int* __restrict__ perm,
    const float* __restrict__ cfFs, const float* __restrict__ cfBs,
    float* __restrict__ tbl_g, float* __restrict__ ct_g)
{
    const int bh = blockIdx.x >> 3, g = blockIdx.x & 7;
    const int tid = threadIdx.x;
    const int sub = tid >> 6, dir = (tid >> 5) & 1, dd = tid & 31;
    const int c = g * 4 + sub;
    const int base = bh * CN + c * 32;
    const float* __restrict__ cf = dir ? cfBs : cfFs;
    const float* __restrict__ hb = h_ws + (size_t)bh * CN * CHD;
    float* __restrict__ tbl = tbl_g + (size_t)bh * TROWS * 64;

    float acc = 0.f;
    #pragma unroll
    for (int bt = 0; bt < 2; ++bt) {
        int jv[16]; float cv[16], hv[16];
        #pragma unroll
        for (int t = 0; t < 16; ++t) {
            const int p16 = bt * 16 + t;
            const int pos = dir ? (31 - p16) : p16;
            jv[t] = perm[base + pos];
            cv[t] = cf[base + pos];
        }
        #pragma unroll
        for (int t = 0; t < 16; ++t)
            hv[t] = hb[(size_t)jv[t] * CHD + dd];        // 16 gathers in flight
        #pragma unroll
        for (int t = 0; t < 16; ++t) {
            const int p16 = bt * 16 + t;
            const int pos = dir ? (31 - p16) : p16;
            const int prow = c * 32 + pos;
            if (dir == 0) {
                tbl[(size_t)prow * 64 + dd] = acc;       // exclusive prefix
                acc += cv[t] * hv[t];
            } else {
                acc += cv[t] * hv[t];
                tbl[(size_t)prow * 64 + 32 + dd] = acc;  // inclusive suffix
            }
        }
    }
    ct_g[(size_t)((bh * 2 + dir) * 32 + c) * 32 + dd] = acc;
}

// ---------------- K4: offsets + binary search + combine ----------------
// 512 blocks x 256 thr; block = (bh, hex of 64 i's); thread = (ii, part of 8 dims).
__global__ __launch_bounds__(256) void out_kernel(
    const float* __restrict__ sarr, const float* __restrict__ dsrt,
    const float* __restrict__ sPBs, const float* __restrict__ sSFs,
    const float* __restrict__ ct_g, float* __restrict__ tbl_g,
    float* __restrict__ out)
{
    __shared__ __align__(16) float dsS[CN];
    __shared__ __align__(16) float ctF[32 * 32], ctB[32 * 32];
    __shared__ __align__(16) float ofF[33 * 32], ofB[33 * 32];

    const int bh = blockIdx.x >> 4, hex = blockIdx.x & 15;
    const int tid = threadIdx.x;
    float* __restrict__ tbl = tbl_g + (size_t)bh * TROWS * 64;

    for (int t = tid; t < CN; t += 256) dsS[t] = dsrt[bh * CN + t];
    for (int t = tid; t < 1024; t += 256) {
        ctF[t] = ct_g[(size_t)(bh * 2 + 0) * 1024 + t];
        ctB[t] = ct_g[(size_t)(bh * 2 + 1) * 1024 + t];
    }
    if (tid < 64) tbl[(size_t)CN * 64 + tid] = 0.f;   // virtual row 1024 (own-block)
    __syncthreads();

    for (int idx = tid; idx < 33 * 32; idx += 256) {
        const int cc = idx >> 5, dd = idx & 31;
        float rF = 0.f;
        for (int c2 = 0; c2 < cc; ++c2) rF += ctF[c2 * 32 + dd];
        ofF[idx] = rF;
        float rB = 0.f;
        for (int c2 = cc + 1; c2 < 32; ++c2) rB += ctB[c2 * 32 + dd];
        ofB[idx] = rB;
    }
    __syncthreads();

    const int ii = tid >> 2, part = tid & 3;
    const int i = hex * 64 + ii;
    const float s = sarr[bh * CN + i];
    const float c1 = __expf(s), c2v = __expf(0.2f * s), thr = -s;
    int lo = 0, hi = CN;
    while (lo < hi) { const int mid = (lo + hi) >> 1; if (dsS[mid] < thr) lo = mid + 1; else hi = mid; }
    const int k = lo, kc = k >> 5;                    // 0..32 (k==1024 -> 32)

    const float PBs = sPBs[bh * SS + k];
    const float SFs = sSFs[bh * SS + k];
    const float inv = 1.0f / (c2v * PBs + c1 * SFs);

    const float4* tr = (const float4*)(tbl + (size_t)k * 64);
    const int b = bh >> 2, hh = bh & 3;
    float4* o = (float4*)(out + (size_t)(b * CN + i) * CF + hh * 32 + part * 8);
    #pragma unroll
    for (int u = 0; u < 2; ++u) {
        const int qq = part * 2 + u;
        const float4 pb4 = tr[qq], sf4 = tr[8 + qq];
        const float4 oa = *(const float4*)(&ofF[kc * 32 + qq * 4]);
        const float4 ob = *(const float4*)(&ofB[kc * 32 + qq * 4]);
        float4 r;
        r.x = (c2v * (pb4.x + oa.x) + c1 * (sf4.x + ob.x)) * inv;
        r.y = (c2v * (pb4.y + oa.y) + c1 * (sf4.y + ob.y)) * inv;
        r.z = (c2v * (pb4.z + oa.z) + c1 * (sf4.z + ob.z)) * inv;
        r.w = (c2v * (pb4.w + oa.w) + c1 * (sf4.w + ob.w)) * inv;
        o[u] = r;
    }
}

extern "C" void kernel_launch(void* const* d_in, const int* in_sizes, int n_in,
                              void* d_out, int out_size, void* d_ws, size_t ws_size,
                              hipStream_t stream) {
    const float* x     = (const float*)d_in[0];
    const float* W     = (const float*)d_in[1];
    const float* a_src = (const float*)d_in[2];
    const float* a_dst = (const float*)d_in[3];
    float* out = (float*)d_out;

    char* ws = (char*)d_ws;
    size_t off = 0;
    float* h_ws = (float*)(ws + off); off += (size_t)CROWS * CF * 4;            // 4 MB
    float* sarr = (float*)(ws + off); off += (size_t)CBH * CN * 4;
    float* darr = (float*)(ws + off); off += (size_t)CBH * CN * 4;
    float* cfF  = (float*)(ws + off); off += (size_t)CBH * CN * 4;
    float* cfB  = (float*)(ws + off); off += (size_t)CBH * CN * 4;
    float* dsrt = (float*)(ws + off); off += (size_t)CBH * CN * 4;
    int*   perm = (int*)  (ws + off); off += (size_t)CBH * CN * 4;
    float* cfFs = (float*)(ws + off); off += (size_t)CBH * CN * 4;
    float* cfBs = (float*)(ws + off); off += (size_t)CBH * CN * 4;
    float* sPBs = (float*)(ws + off); off += (size_t)CBH * SS * 4;
    float* sSFs = (float*)(ws + off); off += (size_t)CBH * SS * 4;
    float* ctg  = (float*)(ws + off); off += (size_t)CBH * 2 * 32 * 32 * 4;     // 256 KB
    float* tblg = (float*)(ws + off); off += (size_t)CBH * TROWS * 64 * 4;      // 8.4 MB
    (void)ws_size;

    proj_kernel<<<512, 256, 0, stream>>>(x, W, a_src, a_dst, h_ws, sarr, darr, cfF, cfB);
    rank_kernel<<<512, 256, 0, stream>>>(darr, cfF, cfB, dsrt, perm, cfFs, cfBs, sPBs, sSFs);
    scan_kernel<<<256, 256, 0, stream>>>(h_ws, perm, cfFs, cfBs, tblg, ctg);
    out_kernel<<<512, 256, 0, stream>>>(sarr, dsrt, sPBs, sSFs, ctg, tblg, out);
}